// Round 4
// baseline (237.312 us; speedup 1.0000x reference)
//
#include <hip/hip_runtime.h>

// NonSpikingInput: RK2 leaky integrator, closed form per step:
//   v' = 0.625*v + 0.075*i   (E_REST = I_BIAS = 0)
// Output = full history, (4096, 8192) fp32. Memory-bound: 268 MB -> ~43 us floor.
//
// R3: LDS round-trip, padded chunks, serial scan. 80.7 us, 2.5 TB/s.
// R4 FAILED-NEUTRAL: persistent pipeline, counted waitcnt. 81.8 us.
// R5 FAILED-NEUTRAL: 8 blocks/CU occupancy. 79.1 us.
// R6 FAILED-NEUTRAL: wave-level affine prefix scan, zero LDS / zero barriers,
//   32 waves/CU, coalesced. 88 us, STILL 2.5 TB/s -> all structural theories
//   dead. Common factor in R3-R6: __builtin_nontemporal_store on every output
//   byte (plus WRITE_SIZE amplification 131->148 MB in R6). fillBuffer (plain
//   stores) sustains 6.7 TB/s in the same runs.
// R7 change: (1) PLAIN stores -- drop the nt flag (primary suspect: nt
//   bypasses L2 retention, degraded write-combine path). (2) SEG 512->1024
//   (16 floats/lane, 4 independent b128 loads in flight/wave, 4 grid-stride
//   iters) -- doubles in-flight bytes in case of residual latency limits.
//   Counter disambiguation: NT-was-it -> WRITE_SIZE ~131 MB + dur ~55 us;
//   MLP-was-it -> dur drops, WRITE_SIZE stays ~148 MB.

typedef float fx4 __attribute__((ext_vector_type(4)));

constexpr int TT  = 8192;   // time steps per row
constexpr int BLK = 256;    // threads per block (4 waves)
constexpr int SEG = 1024;   // steps per wave-segment = 16 floats/lane
constexpr int WPB = BLK / 64;

__global__ __launch_bounds__(BLK, 8)
void neuron_scan(const float* __restrict__ in, float* __restrict__ out,
                 int nseg) {
    const float A    = 0.625f;
    const float Bc   = 0.075f;
    const float A4   = 0.152587890625f;            // exact in fp32
    const float A8   = 2.32830643653869629e-2f;    // exact in fp32
    const float A16  = 5.42101086242752217e-4f;
    const float A32  = 2.93873587705571877e-7f;
    const float A64  = 8.63616855509444463e-14f;
    const float A128 = 7.45834073120020674e-27f;

    const int lane = threadIdx.x & 63;
    const int wid  = blockIdx.x * WPB + (threadIdx.x >> 6);
    const int nw   = gridDim.x * WPB;

    for (int s = wid; s < nseg; s += nw) {
        const int row = s >> 3;            // TT/SEG = 8 segments per row
        const int col = s & 7;
        const size_t base = (size_t)row * TT + (size_t)col * SEG;
        const fx4* src = (const fx4*)(in + base);

        // Coalesced load: wave covers [base, base+4096B); lane owns 64 B
        // contiguous (4 consecutive fx4) = its 16 consecutive timesteps.
        fx4 x0 = src[4 * lane];
        fx4 x1 = src[4 * lane + 1];
        fx4 x2 = src[4 * lane + 2];
        fx4 x3 = src[4 * lane + 3];

        // Warm-up carry: scan the preceding 64 inputs from v=0 (A^64 ~ 9e-14
        // truncation, same policy as R3-R6). Lanes 0..15 hold 4 steps each.
        float vwarm = 0.0f;
        if (col > 0) {                     // uniform branch
            fx4 wx = {0.0f, 0.0f, 0.0f, 0.0f};
            if (lane < 16) wx = src[lane - 16];   // bytes [base-256, base)
            float cw;
            cw = Bc * wx.x;
            cw = fmaf(A, cw, Bc * wx.y);
            cw = fmaf(A, cw, Bc * wx.z);
            cw = fmaf(A, cw, Bc * wx.w);
            float u;
            u = __shfl_up(cw, 1); if (lane >= 1) cw = fmaf(A4,  u, cw);
            u = __shfl_up(cw, 2); if (lane >= 2) cw = fmaf(A8,  u, cw);
            u = __shfl_up(cw, 4); if (lane >= 4) cw = fmaf(A16, u, cw);
            u = __shfl_up(cw, 8); if (lane >= 8) cw = fmaf(A32, u, cw);
            vwarm = __shfl(cw, 15);        // inclusive over all 64 warm steps
        }

        // Local contribution of this lane's 16 steps, starting from v=0.
        float c;
        c = Bc * x0.x;
        c = fmaf(A, c, Bc * x0.y);
        c = fmaf(A, c, Bc * x0.z);
        c = fmaf(A, c, Bc * x0.w);
        c = fmaf(A, c, Bc * x1.x);
        c = fmaf(A, c, Bc * x1.y);
        c = fmaf(A, c, Bc * x1.z);
        c = fmaf(A, c, Bc * x1.w);
        c = fmaf(A, c, Bc * x2.x);
        c = fmaf(A, c, Bc * x2.y);
        c = fmaf(A, c, Bc * x2.z);
        c = fmaf(A, c, Bc * x2.w);
        c = fmaf(A, c, Bc * x3.x);
        c = fmaf(A, c, Bc * x3.y);
        c = fmaf(A, c, Bc * x3.z);
        c = fmaf(A, c, Bc * x3.w);
        // Fold incoming carry into lane 0; scan propagates it with exact
        // A^16k weights (beyond lane 8 distance, A^128 ~ 7e-27 -> negligible).
        if (lane == 0) c = fmaf(A16, vwarm, c);

        // Inclusive affine scan across lanes (uniform per-lane decay A^16).
        float u;
        u = __shfl_up(c, 1); if (lane >= 1) c = fmaf(A16,  u, c);
        u = __shfl_up(c, 2); if (lane >= 2) c = fmaf(A32,  u, c);
        u = __shfl_up(c, 4); if (lane >= 4) c = fmaf(A64,  u, c);
        u = __shfl_up(c, 8); if (lane >= 8) c = fmaf(A128, u, c);

        // v entering this lane's first step = inclusive value of lane-1.
        float venter = __shfl_up(c, 1);
        if (lane == 0) venter = vwarm;

        // Re-run the 16 steps exactly from venter, emitting history in-place.
        float v = venter;
        v = fmaf(A, v, Bc * x0.x); x0.x = v;
        v = fmaf(A, v, Bc * x0.y); x0.y = v;
        v = fmaf(A, v, Bc * x0.z); x0.z = v;
        v = fmaf(A, v, Bc * x0.w); x0.w = v;
        v = fmaf(A, v, Bc * x1.x); x1.x = v;
        v = fmaf(A, v, Bc * x1.y); x1.y = v;
        v = fmaf(A, v, Bc * x1.z); x1.z = v;
        v = fmaf(A, v, Bc * x1.w); x1.w = v;
        v = fmaf(A, v, Bc * x2.x); x2.x = v;
        v = fmaf(A, v, Bc * x2.y); x2.y = v;
        v = fmaf(A, v, Bc * x2.z); x2.z = v;
        v = fmaf(A, v, Bc * x2.w); x2.w = v;
        v = fmaf(A, v, Bc * x3.x); x3.x = v;
        v = fmaf(A, v, Bc * x3.y); x3.y = v;
        v = fmaf(A, v, Bc * x3.z); x3.z = v;
        v = fmaf(A, v, Bc * x3.w); x3.w = v;

        // Coalesced PLAIN store (R7: no nontemporal flag), mirror of load.
        fx4* dst = (fx4*)(out + base);
        dst[4 * lane]     = x0;
        dst[4 * lane + 1] = x1;
        dst[4 * lane + 2] = x2;
        dst[4 * lane + 3] = x3;
    }
}

extern "C" void kernel_launch(void* const* d_in, const int* in_sizes, int n_in,
                              void* d_out, int out_size, void* d_ws, size_t ws_size,
                              hipStream_t stream) {
    const float* in = (const float*)d_in[0];
    float* out = (float*)d_out;
    const int n_rows = in_sizes[0] / TT;          // 4096
    const int nseg = n_rows * (TT / SEG);         // 32768
    int blocks = 2048;                            // 8 blocks/CU, 4 segs/wave
    if (blocks * WPB > nseg) blocks = (nseg + WPB - 1) / WPB;
    neuron_scan<<<dim3(blocks), dim3(BLK), 0, stream>>>(in, out, nseg);
}